// Round 8
// baseline (326.245 us; speedup 1.0000x reference)
//
#include <hip/hip_runtime.h>
#include <hip/hip_bf16.h>
#include <math.h>

// ---------------- problem constants ----------------
#define BATCH 65536
#define NT 256           // 4 waves/block
#define BM 16            // rows per block

using f32x4 = __attribute__((ext_vector_type(4))) float;
using s16x8 = __attribute__((ext_vector_type(8))) short;

#define MFMA16(a, b, c) __builtin_amdgcn_mfma_f32_16x16x32_bf16((a), (b), (c), 0, 0, 0)

__device__ __forceinline__ unsigned short f2bf(float f) {
    unsigned u = __builtin_bit_cast(unsigned, f);
    u = u + 0x7FFFu + ((u >> 16) & 1u);   // RNE
    return (unsigned short)(u >> 16);
}

// A&S 7.1.26 erf, ~13 VALU, branchless; err 1.5e-7
__device__ __forceinline__ float fast_erf(float x) {
    float ax = fabsf(x);
    float t = __builtin_amdgcn_rcpf(fmaf(0.3275911f, ax, 1.0f));
    float poly = t * fmaf(t, fmaf(t, fmaf(t, fmaf(t, 1.061405429f, -1.453152027f),
                                          1.421413741f), -0.284496736f), 0.254829592f);
    float r = 1.0f - poly * __expf(-ax * ax);
    return copysignf(r, x);
}

// swizzled LDS addressing (HBUF rows 1024B, XBUF rows 128B; 16B granule XOR row&7)
__device__ __forceinline__ int hswz(int row, int k) {
    return row * 1024 + ((((k >> 3) ^ (row & 7))) << 4) + ((k & 7) << 1);
}
__device__ __forceinline__ int xaddr(int base, int row, int k) {
    return base + row * 128 + ((((k >> 3) ^ (row & 7))) << 4) + ((k & 7) << 1);
}

// ---------------- weights: f32 [K][N] -> bf16 [N][K] in ws ----------------
__global__ void weights_kernel(const float* __restrict__ W1, const float* __restrict__ W2,
                               const float* __restrict__ W3, unsigned short* __restrict__ wt) {
    __shared__ unsigned short tile[32][33];
    int b = blockIdx.x;
    const float* src; unsigned short* dst; int K, N, kt, nt;
    if (b < 32)       { src = W1; dst = wt;          K = 64;  N = 512; kt = b >> 4;        nt = b & 15; }
    else if (b < 288) { int c = b - 32;  src = W2; dst = wt + 32768;  K = 512; N = 512; kt = c >> 4; nt = c & 15; }
    else              { int c = b - 288; src = W3; dst = wt + 294912; K = 512; N = 64;  kt = c >> 1; nt = c & 1;  }
    int tx = threadIdx.x & 31, ty = threadIdx.x >> 5;
    int k0 = kt * 32, n0 = nt * 32;
#pragma unroll
    for (int i = 0; i < 4; i++) {
        int k = k0 + ty + i * 8;
        tile[tx][ty + i * 8] = f2bf(src[(size_t)k * N + n0 + tx]);
    }
    __syncthreads();
#pragma unroll
    for (int i = 0; i < 4; i++) {
        int n = n0 + ty + i * 8;
        dst[(size_t)n * K + k0 + tx] = tile[ty + i * 8][tx];
    }
}

// ======================= fused kernel: BM=16, 4 waves, 4 blocks/CU =======================
// LDS (byte offsets): HBUF [16][512]bf16 @0 (16KB, swizzled) | XBUF @16384 (2KB)
//                     REDB @18432 (16 rows x 4 waves x {s,q}) | STATB @18944 (16 x {mu,rs})
// epilogue overlay of HBUF: LOGB @0 (16 x 272B), APAD @4352 (16 x 544B)
// launch_bounds(256,4): 128 unified regs/wave (measured need ~116 at this shape) -> no spill,
// 4 waves/SIMD via FOUR independent blocks/CU (phase decorrelation vs 2x8-wave).
#define SMEM16 19072
__global__ __launch_bounds__(NT, 4) void fused_bm16(
    const float* __restrict__ a_bits, const float* __restrict__ shift_bits,
    const float* __restrict__ b1, const float* __restrict__ g1, const float* __restrict__ be1,
    const float* __restrict__ b2, const float* __restrict__ g2, const float* __restrict__ be2,
    const float* __restrict__ b3, const unsigned short* __restrict__ wt,
    float* __restrict__ out) {
    __shared__ char smem[SMEM16];
    const int t = threadIdx.x;
    const int wave = t >> 6, lane = t & 63, g = lane >> 4, ln = lane & 15;
    const int row0 = blockIdx.x * BM;
    const int n0w = wave * 128;          // each wave owns 128 output cols
    const int XB = 16384, RB = 18432, SB = 18944;
    const unsigned short* wt1 = wt;
    const unsigned short* wt2 = wt + 32768;
    const unsigned short* wt3 = wt + 294912;

    // ---- stage shift_bits (16x64 f32 -> bf16 swizzled), 4 elems/thread ----
    {
        int r = t >> 4, c = t & 15;
        float4 x = *(const float4*)(shift_bits + (size_t)(row0 + r) * 64 + c * 4);
        unsigned p0 = (unsigned)f2bf(x.x) | ((unsigned)f2bf(x.y) << 16);
        unsigned p1 = (unsigned)f2bf(x.z) | ((unsigned)f2bf(x.w) << 16);
        uint2 v; v.x = p0; v.y = p1;
        *(uint2*)(smem + XB + r * 128 + (((c >> 1) ^ (r & 7)) << 4) + (c & 1) * 8) = v;
    }
    __syncthreads();

    // per-lane W2 row bases for this wave's 8 col-frags
    const unsigned short* b2base[8];
#pragma unroll
    for (int fn = 0; fn < 8; fn++) b2base[fn] = wt2 + (size_t)(n0w + fn * 16 + ln) * 512;

    // ---- GEMM1: x(16x64) @ W1(64x512) -> acc[8] (this wave's 128 cols) ----
    f32x4 acc[8];
#pragma unroll
    for (int fn = 0; fn < 8; fn++) acc[fn] = (f32x4){0.f, 0.f, 0.f, 0.f};
#pragma unroll
    for (int ks = 0; ks < 2; ks++) {
        s16x8 af = *(const s16x8*)(smem + xaddr(XB, ln, ks * 32 + g * 8));
#pragma unroll
        for (int h = 0; h < 2; h++) {
            s16x8 bf[4];
#pragma unroll
            for (int j = 0; j < 4; j++)
                bf[j] = *(const s16x8*)(wt1 + (size_t)(n0w + (h * 4 + j) * 16 + ln) * 64 + ks * 32 + g * 8);
#pragma unroll
            for (int j = 0; j < 4; j++) acc[h * 4 + j] = MFMA16(af, bf[j], acc[h * 4 + j]);
        }
    }

    // ---- LN1: bias + row partial sums -> REDB ----
    {
        float bb[8];
#pragma unroll
        for (int fn = 0; fn < 8; fn++) bb[fn] = b1[n0w + fn * 16 + ln];
#pragma unroll
        for (int fn = 0; fn < 8; fn++)
#pragma unroll
            for (int r = 0; r < 4; r++) acc[fn][r] += bb[fn];
#pragma unroll
        for (int r = 0; r < 4; r++) {
            float s = 0.f, q = 0.f;
#pragma unroll
            for (int fn = 0; fn < 8; fn++) { float v = acc[fn][r]; s += v; q += v * v; }
#pragma unroll
            for (int m = 1; m < 16; m <<= 1) { s += __shfl_xor(s, m, 64); q += __shfl_xor(q, m, 64); }
            if (ln == 0) {
                int row = g * 4 + r;
                float* rp = (float*)(smem + RB + (row * 4 + wave) * 8);
                rp[0] = s; rp[1] = q;
            }
        }
    }
    __syncthreads();
    if (t < 16) {
        float s = 0.f, q = 0.f;
#pragma unroll
        for (int w = 0; w < 4; w++) {
            float* rp = (float*)(smem + RB + (t * 4 + w) * 8);
            s += rp[0]; q += rp[1];
        }
        float mu = s * (1.0f / 512.0f);
        float var = q * (1.0f / 512.0f) - mu * mu;
        float rs = rsqrtf(var + 1e-5f);
        float* sp = (float*)(smem + SB + t * 8);
        sp[0] = mu; sp[1] = rs;
    }
    __syncthreads();
    // LN1 apply + GELU -> h1 in HBUF
    {
        float gm[8], bt[8];
#pragma unroll
        for (int fn = 0; fn < 8; fn++) { int c = n0w + fn * 16 + ln; gm[fn] = g1[c]; bt[fn] = be1[c]; }
#pragma unroll
        for (int r = 0; r < 4; r++) {
            int row = g * 4 + r;
            float* sp = (float*)(smem + SB + row * 8);
            float mu = sp[0], rs = sp[1];
#pragma unroll
            for (int fn = 0; fn < 8; fn++) {
                float y = (acc[fn][r] - mu) * rs * gm[fn] + bt[fn];
                float ge = 0.5f * y * (1.0f + fast_erf(y * 0.70710678118654752f));
                *(unsigned short*)(smem + hswz(row, n0w + fn * 16 + ln)) = f2bf(ge);
            }
        }
    }
    __syncthreads();

    // ---- GEMM2: h1(16x512) @ W2(512x512) -> acc[8], B direct from L2, fn halves ----
#pragma unroll
    for (int fn = 0; fn < 8; fn++) acc[fn] = (f32x4){0.f, 0.f, 0.f, 0.f};
#pragma unroll
    for (int step = 0; step < 16; step++) {
        s16x8 af = *(const s16x8*)(smem + hswz(ln, step * 32 + g * 8));
#pragma unroll
        for (int h = 0; h < 2; h++) {
            s16x8 bf[4];
#pragma unroll
            for (int j = 0; j < 4; j++)
                bf[j] = *(const s16x8*)(b2base[h * 4 + j] + step * 32 + g * 8);
#pragma unroll
            for (int j = 0; j < 4; j++) acc[h * 4 + j] = MFMA16(af, bf[j], acc[h * 4 + j]);
        }
    }

    // ---- LN2: bias + row partials ----
    {
        float bb[8];
#pragma unroll
        for (int fn = 0; fn < 8; fn++) bb[fn] = b2[n0w + fn * 16 + ln];
#pragma unroll
        for (int fn = 0; fn < 8; fn++)
#pragma unroll
            for (int r = 0; r < 4; r++) acc[fn][r] += bb[fn];
#pragma unroll
        for (int r = 0; r < 4; r++) {
            float s = 0.f, q = 0.f;
#pragma unroll
            for (int fn = 0; fn < 8; fn++) { float v = acc[fn][r]; s += v; q += v * v; }
#pragma unroll
            for (int m = 1; m < 16; m <<= 1) { s += __shfl_xor(s, m, 64); q += __shfl_xor(q, m, 64); }
            if (ln == 0) {
                int row = g * 4 + r;
                float* rp = (float*)(smem + RB + (row * 4 + wave) * 8);
                rp[0] = s; rp[1] = q;
            }
        }
    }
    __syncthreads();
    if (t < 16) {
        float s = 0.f, q = 0.f;
#pragma unroll
        for (int w = 0; w < 4; w++) {
            float* rp = (float*)(smem + RB + (t * 4 + w) * 8);
            s += rp[0]; q += rp[1];
        }
        float mu = s * (1.0f / 512.0f);
        float var = q * (1.0f / 512.0f) - mu * mu;
        float rs = rsqrtf(var + 1e-5f);
        float* sp = (float*)(smem + SB + t * 8);
        sp[0] = mu; sp[1] = rs;
    }
    __syncthreads();
    // LN2 apply + GELU -> h2 overwrites HBUF
    {
        float gm[8], bt[8];
#pragma unroll
        for (int fn = 0; fn < 8; fn++) { int c = n0w + fn * 16 + ln; gm[fn] = g2[c]; bt[fn] = be2[c]; }
#pragma unroll
        for (int r = 0; r < 4; r++) {
            int row = g * 4 + r;
            float* sp = (float*)(smem + SB + row * 8);
            float mu = sp[0], rs = sp[1];
#pragma unroll
            for (int fn = 0; fn < 8; fn++) {
                float y = (acc[fn][r] - mu) * rs * gm[fn] + bt[fn];
                float ge = 0.5f * y * (1.0f + fast_erf(y * 0.70710678118654752f));
                *(unsigned short*)(smem + hswz(row, n0w + fn * 16 + ln)) = f2bf(ge);
            }
        }
    }
    __syncthreads();

    // ---- GEMM3: h2(16x512) @ W3(512x64): wave q=wave owns cols q*16..q*16+15; dual acc ----
    const int q = wave;
    float b3v = b3[q * 16 + ln];
    const unsigned short* b3base = wt3 + (size_t)(q * 16 + ln) * 512;
    f32x4 acc3a = (f32x4){0.f, 0.f, 0.f, 0.f};
    f32x4 acc3b = (f32x4){0.f, 0.f, 0.f, 0.f};
#pragma unroll
    for (int ks = 0; ks < 16; ks += 2) {
        s16x8 bfr0 = *(const s16x8*)(b3base + ks * 32 + g * 8);
        s16x8 bfr1 = *(const s16x8*)(b3base + (ks + 1) * 32 + g * 8);
        s16x8 af0 = *(const s16x8*)(smem + hswz(ln, ks * 32 + g * 8));
        s16x8 af1 = *(const s16x8*)(smem + hswz(ln, (ks + 1) * 32 + g * 8));
        acc3a = MFMA16(af0, bfr0, acc3a);
        acc3b = MFMA16(af1, bfr1, acc3b);
    }
    __syncthreads();

    // ---- logits (+b3) into LOGB; zero-padded a-tile into APAD (HBUF dead) ----
    const int LOGB = 0, ABUF = 4352, LST = 272, AST = 544;
#pragma unroll
    for (int r = 0; r < 4; r++) {
        int row = g * 4 + r;
        *(float*)(smem + LOGB + row * LST + (q * 16 + ln) * 4) = acc3a[r] + acc3b[r] + b3v;
    }
    {
        int r = t >> 4, c0 = (t & 15) * 4;
        float* ap = (float*)(smem + ABUF + r * AST);
        float4 z4 = {0.f, 0.f, 0.f, 0.f};
        *(float4*)(ap + c0) = z4;
        float4 av = *(const float4*)(a_bits + (size_t)(row0 + r) * 64 + c0);
        *(float4*)(ap + 64 + c0) = av;
    }
    __syncthreads();

    // ---- softmax over 64 (16 thr/row, 4 cols each) ----
    {
        int r = t >> 4, c0 = (t & 15) * 4;
        float* lp = (float*)(smem + LOGB + r * LST + c0 * 4);
        float4 v = *(float4*)lp;
        float mx = fmaxf(fmaxf(v.x, v.y), fmaxf(v.z, v.w));
#pragma unroll
        for (int d = 1; d < 16; d <<= 1) mx = fmaxf(mx, __shfl_xor(mx, d, 64));
        float e0 = __expf(v.x - mx), e1 = __expf(v.y - mx);
        float e2 = __expf(v.z - mx), e3 = __expf(v.w - mx);
        float s = e0 + e1 + e2 + e3;
#pragma unroll
        for (int d = 1; d < 16; d <<= 1) s += __shfl_xor(s, d, 64);
        float inv = 1.0f / s;
        float4 o; o.x = e0 * inv; o.y = e1 * inv; o.z = e2 * inv; o.w = e3 * inv;
        *(float4*)lp = o;
    }
    __syncthreads();

    // ---- causal conv: 16 thr/row, 4 outs/thread, zero-padded sliding window ----
    {
        int r = t >> 4, i0 = (t & 15) * 4;
        const float* prow = (const float*)(smem + LOGB + r * LST);
        const float* apad = (const float*)(smem + ABUF + r * AST);
        float W[8];
        {
            float4 wa = *(const float4*)(apad + i0 + 60);
            float4 wb = *(const float4*)(apad + i0 + 64);
            W[0] = wa.x; W[1] = wa.y; W[2] = wa.z; W[3] = wa.w;
            W[4] = wb.x; W[5] = wb.y; W[6] = wb.z; W[7] = wb.w;
        }
        float o0 = 0.f, o1 = 0.f, o2 = 0.f, o3 = 0.f;
#pragma unroll
        for (int s4 = 0; s4 < 16; s4++) {
            float4 p4 = *(const float4*)(prow + 4 * s4);
            o0 = fmaf(p4.x, W[4], fmaf(p4.y, W[3], fmaf(p4.z, W[2], fmaf(p4.w, W[1], o0))));
            o1 = fmaf(p4.x, W[5], fmaf(p4.y, W[4], fmaf(p4.z, W[3], fmaf(p4.w, W[2], o1))));
            o2 = fmaf(p4.x, W[6], fmaf(p4.y, W[5], fmaf(p4.z, W[4], fmaf(p4.w, W[3], o2))));
            o3 = fmaf(p4.x, W[7], fmaf(p4.y, W[6], fmaf(p4.z, W[5], fmaf(p4.w, W[4], o3))));
            if (s4 < 15) {
                W[4] = W[0]; W[5] = W[1]; W[6] = W[2]; W[7] = W[3];
                float4 nw = *(const float4*)(apad + i0 + 56 - 4 * s4);
                W[0] = nw.x; W[1] = nw.y; W[2] = nw.z; W[3] = nw.w;
            }
        }
        float4 o; o.x = o0; o.y = o1; o.z = o2; o.w = o3;
        *(float4*)(out + (size_t)(row0 + r) * 64 + i0) = o;
    }
}

extern "C" void kernel_launch(void* const* d_in, const int* in_sizes, int n_in,
                              void* d_out, int out_size, void* d_ws, size_t ws_size,
                              hipStream_t stream) {
    const float* a_bits = (const float*)d_in[0];
    const float* shift  = (const float*)d_in[1];
    const float* W1  = (const float*)d_in[2];
    const float* b1  = (const float*)d_in[3];
    const float* g1  = (const float*)d_in[4];
    const float* be1 = (const float*)d_in[5];
    const float* W2  = (const float*)d_in[6];
    const float* b2  = (const float*)d_in[7];
    const float* g2  = (const float*)d_in[8];
    const float* be2 = (const float*)d_in[9];
    const float* W3  = (const float*)d_in[10];
    const float* b3  = (const float*)d_in[11];
    float* out = (float*)d_out;
    unsigned short* wt = (unsigned short*)d_ws;

    weights_kernel<<<320, 256, 0, stream>>>(W1, W2, W3, wt);
    fused_bm16<<<BATCH / BM, NT, 0, stream>>>(a_bits, shift, b1, g1, be1,
                                              b2, g2, be2, b3, wt, out);
}

// Round 9
// 217.463 us; speedup vs baseline: 1.5002x; 1.5002x over previous
//
#include <hip/hip_runtime.h>
#include <hip/hip_bf16.h>
#include <math.h>

// ---------------- problem constants ----------------
#define BATCH 65536
#define NT 512           // 8 waves/block
#define BM 32            // rows per block

using f32x4 = __attribute__((ext_vector_type(4))) float;
using s16x8 = __attribute__((ext_vector_type(8))) short;

#define MFMA16(a, b, c) __builtin_amdgcn_mfma_f32_16x16x32_bf16((a), (b), (c), 0, 0, 0)

__device__ __forceinline__ unsigned short f2bf(float f) {
    unsigned u = __builtin_bit_cast(unsigned, f);
    u = u + 0x7FFFu + ((u >> 16) & 1u);   // RNE
    return (unsigned short)(u >> 16);
}

// A&S 7.1.26 erf, ~13 VALU, branchless; err 1.5e-7
__device__ __forceinline__ float fast_erf(float x) {
    float ax = fabsf(x);
    float t = __builtin_amdgcn_rcpf(fmaf(0.3275911f, ax, 1.0f));
    float poly = t * fmaf(t, fmaf(t, fmaf(t, fmaf(t, 1.061405429f, -1.453152027f),
                                          1.421413741f), -0.284496736f), 0.254829592f);
    float r = 1.0f - poly * __expf(-ax * ax);
    return copysignf(r, x);
}

// swizzled LDS addressing (HBUF rows 1024B, XBUF rows 128B; 16B granule XOR row&7)
__device__ __forceinline__ int hswz(int row, int k) {
    return row * 1024 + ((((k >> 3) ^ (row & 7))) << 4) + ((k & 7) << 1);
}
__device__ __forceinline__ int xaddr(int base, int row, int k) {
    return base + row * 128 + ((((k >> 3) ^ (row & 7))) << 4) + ((k & 7) << 1);
}

// ---------------- weights: f32 [K][N] -> bf16 [N][K] in ws ----------------
__global__ void weights_kernel(const float* __restrict__ W1, const float* __restrict__ W2,
                               const float* __restrict__ W3, unsigned short* __restrict__ wt) {
    __shared__ unsigned short tile[32][33];
    int b = blockIdx.x;
    const float* src; unsigned short* dst; int K, N, kt, nt;
    if (b < 32)       { src = W1; dst = wt;          K = 64;  N = 512; kt = b >> 4;        nt = b & 15; }
    else if (b < 288) { int c = b - 32;  src = W2; dst = wt + 32768;  K = 512; N = 512; kt = c >> 4; nt = c & 15; }
    else              { int c = b - 288; src = W3; dst = wt + 294912; K = 512; N = 64;  kt = c >> 1; nt = c & 1;  }
    int tx = threadIdx.x & 31, ty = threadIdx.x >> 5;
    int k0 = kt * 32, n0 = nt * 32;
#pragma unroll
    for (int i = 0; i < 4; i++) {
        int k = k0 + ty + i * 8;
        tile[tx][ty + i * 8] = f2bf(src[(size_t)k * N + n0 + tx]);
    }
    __syncthreads();
#pragma unroll
    for (int i = 0; i < 4; i++) {
        int n = n0 + ty + i * 8;
        dst[(size_t)n * K + k0 + tx] = tile[ty + i * 8][tx];
    }
}

// ---------------- LN helpers ----------------
__device__ __forceinline__ void ln_reduce(f32x4 (&acc)[2][4], const float* __restrict__ bias,
                                          char* smem, int redb, int n0w, int ln, int g, int wave) {
    float bb[4];
#pragma unroll
    for (int fn = 0; fn < 4; fn++) bb[fn] = bias[n0w + fn * 16 + ln];
#pragma unroll
    for (int fm = 0; fm < 2; fm++)
#pragma unroll
        for (int fn = 0; fn < 4; fn++)
#pragma unroll
            for (int r = 0; r < 4; r++) acc[fm][fn][r] += bb[fn];
#pragma unroll
    for (int fm = 0; fm < 2; fm++)
#pragma unroll
        for (int r = 0; r < 4; r++) {
            float s = 0.f, q = 0.f;
#pragma unroll
            for (int fn = 0; fn < 4; fn++) { float v = acc[fm][fn][r]; s += v; q += v * v; }
#pragma unroll
            for (int m = 1; m < 16; m <<= 1) { s += __shfl_xor(s, m, 64); q += __shfl_xor(q, m, 64); }
            if (ln == 0) {
                int row = fm * 16 + g * 4 + r;
                float* rp = (float*)(smem + redb + (row * 8 + wave) * 8);
                rp[0] = s; rp[1] = q;
            }
        }
}

__device__ __forceinline__ void ln_stats(char* smem, int redb, int statb, int t) {
    if (t < 32) {
        float s = 0.f, q = 0.f;
#pragma unroll
        for (int w = 0; w < 8; w++) {
            float* rp = (float*)(smem + redb + (t * 8 + w) * 8);
            s += rp[0]; q += rp[1];
        }
        float mu = s * (1.0f / 512.0f);
        float var = q * (1.0f / 512.0f) - mu * mu;
        float rs = rsqrtf(var + 1e-5f);
        float* sp = (float*)(smem + statb + t * 8);
        sp[0] = mu; sp[1] = rs;
    }
}

__device__ __forceinline__ void ln_apply(f32x4 (&acc)[2][4], const float* __restrict__ gamma,
                                         const float* __restrict__ beta, char* smem,
                                         int statb, int n0w, int ln, int g) {
    float gm[4], bt[4];
#pragma unroll
    for (int fn = 0; fn < 4; fn++) { int c = n0w + fn * 16 + ln; gm[fn] = gamma[c]; bt[fn] = beta[c]; }
#pragma unroll
    for (int fm = 0; fm < 2; fm++)
#pragma unroll
        for (int r = 0; r < 4; r++) {
            int row = fm * 16 + g * 4 + r;
            float* sp = (float*)(smem + statb + row * 8);
            float mu = sp[0], rs = sp[1];
#pragma unroll
            for (int fn = 0; fn < 4; fn++) {
                int col = n0w + fn * 16 + ln;
                float y = (acc[fm][fn][r] - mu) * rs * gm[fn] + bt[fn];
                float ge = 0.5f * y * (1.0f + fast_erf(y * 0.70710678118654752f));
                *(unsigned short*)(smem + hswz(row, col)) = f2bf(ge);
            }
        }
}

// ======================= fused kernel: BM=32, 8 waves, (512,4) =======================
// LDS: HBUF [32][512]bf16 = 32KB | XBUF @32768 (4KB) | REDB @36864 (2KB) | STATB @38912
// epilogue overlay of HBUF: LOGB @0 (32x272B), APAD @8704 (32x544B)
// launch_bounds(512,4): cap 128 unified. Measured body = 84 regs (R6, no spill);
// +16 (GEMM2 depth-2 B pipeline) +4 (early a_bits) ~= 104 -> still no spill.
#define SMEM32 39168
__global__ __launch_bounds__(NT, 4) void fused_v9(
    const float* __restrict__ a_bits, const float* __restrict__ shift_bits,
    const float* __restrict__ b1, const float* __restrict__ g1, const float* __restrict__ be1,
    const float* __restrict__ b2, const float* __restrict__ g2, const float* __restrict__ be2,
    const float* __restrict__ b3, const unsigned short* __restrict__ wt,
    float* __restrict__ out) {
    __shared__ char smem[SMEM32];
    const int t = threadIdx.x;
    const int wave = t >> 6, lane = t & 63, g = lane >> 4, ln = lane & 15;
    const int row0 = blockIdx.x * BM;
    const int n0w = wave * 64;
    const int XB = 32768, RB = 36864, SB = 38912;
    const unsigned short* wt1 = wt;
    const unsigned short* wt2 = wt + 32768;
    const unsigned short* wt3 = wt + 294912;

    // stage shift_bits (32x64 f32 -> bf16 swizzled)
    {
        int r = t >> 4, c = t & 15;
        float4 x = *(const float4*)(shift_bits + (size_t)(row0 + r) * 64 + c * 4);
        unsigned p0 = (unsigned)f2bf(x.x) | ((unsigned)f2bf(x.y) << 16);
        unsigned p1 = (unsigned)f2bf(x.z) | ((unsigned)f2bf(x.w) << 16);
        uint2 v; v.x = p0; v.y = p1;
        *(uint2*)(smem + XB + r * 128 + (((c >> 1) ^ (r & 7)) << 4) + (c & 1) * 8) = v;
    }
    __syncthreads();

    const unsigned short* b2base[4];
#pragma unroll
    for (int fn = 0; fn < 4; fn++) b2base[fn] = wt2 + (size_t)(n0w + fn * 16 + ln) * 512;

    // GEMM1: x(32x64) @ W1 -> acc[2][4]
    f32x4 acc[2][4];
#pragma unroll
    for (int fm = 0; fm < 2; fm++)
#pragma unroll
        for (int fn = 0; fn < 4; fn++) acc[fm][fn] = (f32x4){0.f, 0.f, 0.f, 0.f};
#pragma unroll
    for (int ks = 0; ks < 2; ks++) {
        s16x8 af[2], bf[4];
#pragma unroll
        for (int fn = 0; fn < 4; fn++)
            bf[fn] = *(const s16x8*)(wt1 + (size_t)(n0w + fn * 16 + ln) * 64 + ks * 32 + g * 8);
#pragma unroll
        for (int fm = 0; fm < 2; fm++)
            af[fm] = *(const s16x8*)(smem + xaddr(XB, fm * 16 + ln, ks * 32 + g * 8));
#pragma unroll
        for (int fm = 0; fm < 2; fm++)
#pragma unroll
            for (int fn = 0; fn < 4; fn++) acc[fm][fn] = MFMA16(af[fm], bf[fn], acc[fm][fn]);
    }

    // LN1+GELU -> h1
    ln_reduce(acc, b1, smem, RB, n0w, ln, g, wave);
    __syncthreads();
    ln_stats(smem, RB, SB, t);
    __syncthreads();
    ln_apply(acc, g1, be1, smem, SB, n0w, ln, g);
    __syncthreads();

    // GEMM2: h1(32x512) @ W2, B from L2 with depth-2 register pipeline
#pragma unroll
    for (int fm = 0; fm < 2; fm++)
#pragma unroll
        for (int fn = 0; fn < 4; fn++) acc[fm][fn] = (f32x4){0.f, 0.f, 0.f, 0.f};
    {
        s16x8 bcur[4], bnxt[4];
#pragma unroll
        for (int fn = 0; fn < 4; fn++) bcur[fn] = *(const s16x8*)(b2base[fn] + g * 8);
#pragma unroll
        for (int step = 0; step < 16; step++) {
            if (step < 15) {
#pragma unroll
                for (int fn = 0; fn < 4; fn++)
                    bnxt[fn] = *(const s16x8*)(b2base[fn] + (step + 1) * 32 + g * 8);
            }
            s16x8 af[2];
#pragma unroll
            for (int fm = 0; fm < 2; fm++)
                af[fm] = *(const s16x8*)(smem + hswz(fm * 16 + ln, step * 32 + g * 8));
#pragma unroll
            for (int fm = 0; fm < 2; fm++)
#pragma unroll
                for (int fn = 0; fn < 4; fn++) acc[fm][fn] = MFMA16(af[fm], bcur[fn], acc[fm][fn]);
#pragma unroll
            for (int fn = 0; fn < 4; fn++) bcur[fn] = bnxt[fn];   // SSA-renamed after unroll
        }
    }

    // early a_bits load: latency hides under LN2 + GEMM3 (consumed in epilogue)
    float4 areg;
    {
        int r = t >> 4, c0 = (t & 15) * 4;
        areg = *(const float4*)(a_bits + (size_t)(row0 + r) * 64 + c0);
    }

    // LN2+GELU -> h2 (overwrites HBUF after barrier)
    ln_reduce(acc, b2, smem, RB, n0w, ln, g, wave);
    __syncthreads();
    ln_stats(smem, RB, SB, t);
    __syncthreads();
    ln_apply(acc, g2, be2, smem, SB, n0w, ln, g);
    __syncthreads();

    // GEMM3: h2(32x512) @ W3(512x64): one 16x16 tile per wave, even/odd-k dual acc
    const int mh = wave >> 2, q = wave & 3;
    float b3v = b3[q * 16 + ln];
    const unsigned short* b3base = wt3 + (size_t)(q * 16 + ln) * 512;
    f32x4 acc3a = (f32x4){0.f, 0.f, 0.f, 0.f};
    f32x4 acc3b = (f32x4){0.f, 0.f, 0.f, 0.f};
#pragma unroll
    for (int ks = 0; ks < 16; ks += 2) {
        s16x8 bfr0 = *(const s16x8*)(b3base + ks * 32 + g * 8);
        s16x8 bfr1 = *(const s16x8*)(b3base + (ks + 1) * 32 + g * 8);
        s16x8 af0 = *(const s16x8*)(smem + hswz(mh * 16 + ln, ks * 32 + g * 8));
        s16x8 af1 = *(const s16x8*)(smem + hswz(mh * 16 + ln, (ks + 1) * 32 + g * 8));
        acc3a = MFMA16(af0, bfr0, acc3a);
        acc3b = MFMA16(af1, bfr1, acc3b);
    }
    __syncthreads();

    // logits + zero-padded a-tile (overlay HBUF, now dead)
    const int LOGB = 0, ABUF = 8704, LST = 272, AST = 544;
#pragma unroll
    for (int r = 0; r < 4; r++) {
        int row = mh * 16 + g * 4 + r;
        *(float*)(smem + LOGB + row * LST + (q * 16 + ln) * 4) = acc3a[r] + acc3b[r] + b3v;
    }
    {
        int r = t >> 4, c0 = (t & 15) * 4;
        float* ap = (float*)(smem + ABUF + r * AST);
        float4 z4 = {0.f, 0.f, 0.f, 0.f};
        *(float4*)(ap + c0) = z4;
        *(float4*)(ap + 64 + c0) = areg;
    }
    __syncthreads();

    // softmax over 64 (16 thr/row)
    {
        int r = t >> 4, c0 = (t & 15) * 4;
        float* lp = (float*)(smem + LOGB + r * LST + c0 * 4);
        float4 v = *(float4*)lp;
        float mx = fmaxf(fmaxf(v.x, v.y), fmaxf(v.z, v.w));
#pragma unroll
        for (int d = 1; d < 16; d <<= 1) mx = fmaxf(mx, __shfl_xor(mx, d, 64));
        float e0 = __expf(v.x - mx), e1 = __expf(v.y - mx);
        float e2 = __expf(v.z - mx), e3 = __expf(v.w - mx);
        float s = e0 + e1 + e2 + e3;
#pragma unroll
        for (int d = 1; d < 16; d <<= 1) s += __shfl_xor(s, d, 64);
        float inv = 1.0f / s;
        float4 o; o.x = e0 * inv; o.y = e1 * inv; o.z = e2 * inv; o.w = e3 * inv;
        *(float4*)lp = o;
    }
    __syncthreads();

    // causal conv, 16 thr/row, 4 outs/thread, zero-padded sliding window
    {
        int r = t >> 4, i0 = (t & 15) * 4;
        const float* prow = (const float*)(smem + LOGB + r * LST);
        const float* apad = (const float*)(smem + ABUF + r * AST);
        float W[8];
        {
            float4 wa = *(const float4*)(apad + i0 + 60);
            float4 wb = *(const float4*)(apad + i0 + 64);
            W[0] = wa.x; W[1] = wa.y; W[2] = wa.z; W[3] = wa.w;
            W[4] = wb.x; W[5] = wb.y; W[6] = wb.z; W[7] = wb.w;
        }
        float o0 = 0.f, o1 = 0.f, o2 = 0.f, o3 = 0.f;
#pragma unroll
        for (int s4 = 0; s4 < 16; s4++) {
            float4 p4 = *(const float4*)(prow + 4 * s4);
            o0 = fmaf(p4.x, W[4], fmaf(p4.y, W[3], fmaf(p4.z, W[2], fmaf(p4.w, W[1], o0))));
            o1 = fmaf(p4.x, W[5], fmaf(p4.y, W[4], fmaf(p4.z, W[3], fmaf(p4.w, W[2], o1))));
            o2 = fmaf(p4.x, W[6], fmaf(p4.y, W[5], fmaf(p4.z, W[4], fmaf(p4.w, W[3], o2))));
            o3 = fmaf(p4.x, W[7], fmaf(p4.y, W[6], fmaf(p4.z, W[5], fmaf(p4.w, W[4], o3))));
            if (s4 < 15) {
                W[4] = W[0]; W[5] = W[1]; W[6] = W[2]; W[7] = W[3];
                float4 nw = *(const float4*)(apad + i0 + 56 - 4 * s4);
                W[0] = nw.x; W[1] = nw.y; W[2] = nw.z; W[3] = nw.w;
            }
        }
        float4 o; o.x = o0; o.y = o1; o.z = o2; o.w = o3;
        *(float4*)(out + (size_t)(row0 + r) * 64 + i0) = o;
    }
}

extern "C" void kernel_launch(void* const* d_in, const int* in_sizes, int n_in,
                              void* d_out, int out_size, void* d_ws, size_t ws_size,
                              hipStream_t stream) {
    const float* a_bits = (const float*)d_in[0];
    const float* shift  = (const float*)d_in[1];
    const float* W1  = (const float*)d_in[2];
    const float* b1  = (const float*)d_in[3];
    const float* g1  = (const float*)d_in[4];
    const float* be1 = (const float*)d_in[5];
    const float* W2  = (const float*)d_in[6];
    const float* b2  = (const float*)d_in[7];
    const float* g2  = (const float*)d_in[8];
    const float* be2 = (const float*)d_in[9];
    const float* W3  = (const float*)d_in[10];
    const float* b3  = (const float*)d_in[11];
    float* out = (float*)d_out;
    unsigned short* wt = (unsigned short*)d_ws;

    weights_kernel<<<320, 256, 0, stream>>>(W1, W2, W3, wt);
    fused_v9<<<BATCH / BM, NT, 0, stream>>>(a_bits, shift, b1, g1, be1,
                                            b2, g2, be2, b3, wt, out);
}